// Round 3
// baseline (1034.626 us; speedup 1.0000x reference)
//
#include <hip/hip_runtime.h>
#include <hip/hip_bf16.h>
#include <math.h>

#define NEC 200000
#define NRC 500
#define DD 128
#define LLC 2
#define NNODE 32768
#define EEDGE 262144
#define BBATCH 256

typedef __attribute__((ext_vector_type(8))) short short8;
typedef __attribute__((ext_vector_type(4))) float floatx4;

__device__ __forceinline__ float bf2f(unsigned short u) {
  union { unsigned int i; float f; } c; c.i = ((unsigned int)u) << 16; return c.f;
}
__device__ __forceinline__ unsigned short f2bf(float f) {
  union { float f; unsigned int i; } c; c.f = f;
  unsigned int x = c.i;
  unsigned int r = x + 0x7fffu + ((x >> 16) & 1u);
  return (unsigned short)(r >> 16);
}

// Detect input storage dtype. If ent_emb is fp32, the LOW u16 of each u32 is
// fp32-mantissa junk -> reinterpreted-as-bf16 magnitude >100 w.h.p. If it is
// genuinely bf16 (values ~N(0,0.05)), max |value| ~ 0.3. mode=1 -> fp32.
__global__ void k_detect(const unsigned int* ent_u32, int* mode) {
  int t = threadIdx.x;
  float best = 0.f;
  for (int i = 0; i < 16; ++i) {
    unsigned int w = ent_u32[t * 16 + i];
    float lo = fabsf(bf2f((unsigned short)(w & 0xffffu)));
    if (lo > best) best = lo;  // NaN filtered (NaN>x is false)
  }
  for (int o = 32; o > 0; o >>= 1) {
    float n = __shfl_down(best, o);
    if (n > best) best = n;
  }
  __shared__ float wmax[4];
  if ((t & 63) == 0) wmax[t >> 6] = best;
  __syncthreads();
  if (t == 0) {
    float m = fmaxf(fmaxf(wmax[0], wmax[1]), fmaxf(wmax[2], wmax[3]));
    mode[0] = (m > 100.f) ? 1 : 0;
  }
}

// scale * rel_prior, fp32
__global__ void k_pri(const void* prior, const int* mode, float* pris) {
  int r = blockIdx.x * 256 + threadIdx.x;
  if (r >= NRC) return;
  float p = mode[0] ? ((const float*)prior)[r] : bf2f(((const unsigned short*)prior)[r]);
  pris[r] = p * 0.17677669529663687f; // 1/sqrt(32)
}

// rel_k[l][r][:] = rel_emb[r] @ Wek[l]; rel_v likewise. grid (NR, L, 2), block 128
__global__ void k_rel(const void* rel, const void* Wek, const void* Wev,
                      const int* mode, float* relk, float* relv) {
  int r = blockIdx.x, l = blockIdx.y, which = blockIdx.z;
  int d = threadIdx.x;
  bool fm = mode[0] != 0;
  size_t wofs = (size_t)l * DD * DD;
  const float* Wf = (const float*)(which ? Wev : Wek) + wofs;
  const unsigned short* Wb = (const unsigned short*)(which ? Wev : Wek) + wofs;
  __shared__ float re[DD];
  re[d] = fm ? ((const float*)rel)[r * DD + d] : bf2f(((const unsigned short*)rel)[r * DD + d]);
  __syncthreads();
  float acc = 0.f;
  if (fm) { for (int c = 0; c < DD; ++c) acc += re[c] * Wf[c * DD + d]; }
  else    { for (int c = 0; c < DD; ++c) acc += re[c] * bf2f(Wb[c * DD + d]); }
  float* out = which ? relv : relk;
  out[((size_t)l * NRC + r) * DD + d] = acc;
}

// h = ent_emb[x] : fp32 copy + bf16 copy. Thread per 2-element pair.
__global__ void k_gather(const void* ent, const int* x, const int* mode,
                         float* h, unsigned short* hbf) {
  int t = blockIdx.x * 256 + threadIdx.x; // 0..NN*64-1
  int n = t >> 6, p = t & 63;
  int row = x[n];
  float2 f;
  if (mode[0]) {
    f = ((const float2*)((const float*)ent + (size_t)row * DD))[p];
  } else {
    unsigned int v = ((const unsigned int*)((const unsigned short*)ent + (size_t)row * DD))[p];
    f.x = bf2f((unsigned short)(v & 0xffffu));
    f.y = bf2f((unsigned short)(v >> 16));
  }
  ((unsigned int*)hbf)[t] = ((unsigned int)f2bf(f.y) << 16) | (unsigned int)f2bf(f.x);
  ((float2*)h)[t] = f;
}

// count + scatter in one pass (fixed cap 64; dst ~ Poisson(8), overflow impossible)
__global__ void k_bucket(const int* ei, int* deg, int* bucket) {
  int e = blockIdx.x * 256 + threadIdx.x;
  if (e >= EEDGE) return;
  int dst = ei[EEDGE + e];
  int pos = atomicAdd(&deg[dst], 1);
  if (pos < 64) bucket[dst * 64 + pos] = e;
}

// stage W (either dtype) transposed into LDS as bf16
__device__ __forceinline__ void stage_w(const void* W, bool fm, int tid,
                                        unsigned short (*Wt)[136]) {
  const float* Wf = (const float*)W;
  const unsigned short* Wb = (const unsigned short*)W;
  for (int pass = 0; pass < 8; ++pass) {
    int idx = pass * 256 + tid;
    int c = idx >> 4;
    int d0 = (idx & 15) << 3;
    if (fm) {
      #pragma unroll
      for (int j = 0; j < 8; ++j) Wt[d0 + j][c] = f2bf(Wf[c * DD + d0 + j]);
    } else {
      short8 v = *reinterpret_cast<const short8*>(Wb + c * DD + d0);
      #pragma unroll
      for (int j = 0; j < 8; ++j) Wt[d0 + j][c] = (unsigned short)v[j];
    }
  }
}

// Q/K/V = hbf @ W{q,k,v}[layer].  grid (512, 3), block 256 (4 waves, 64 rows/block)
__global__ __launch_bounds__(256) void k_gemm_qkv(const unsigned short* A,
    const void* Wq, const void* Wk, const void* Wv, const int* mode,
    int layer, unsigned short* Qo, unsigned short* Ko, unsigned short* Vo) {
  __shared__ unsigned short Wt[DD][136]; // transposed W, +8 pad breaks bank conflicts
  const void* W; unsigned short* O;
  if (blockIdx.y == 0)      { W = Wq; O = Qo; }
  else if (blockIdx.y == 1) { W = Wk; O = Ko; }
  else                      { W = Wv; O = Vo; }
  bool fm = mode[0] != 0;
  W = fm ? (const void*)((const float*)W + (size_t)layer * DD * DD)
         : (const void*)((const unsigned short*)W + (size_t)layer * DD * DD);
  int tid = threadIdx.x;
  stage_w(W, fm, tid, Wt);
  __syncthreads();
  int w = tid >> 6, lane = tid & 63;
  int m = lane & 15, quad = lane >> 4;
  int row = blockIdx.x * 64 + w * 16 + m;
  floatx4 acc[8];
  #pragma unroll
  for (int t = 0; t < 8; ++t) acc[t] = (floatx4){0.f, 0.f, 0.f, 0.f};
  const unsigned short* arow = A + (size_t)row * DD;
  #pragma unroll
  for (int ks = 0; ks < 4; ++ks) {
    short8 a = *reinterpret_cast<const short8*>(arow + ks * 32 + quad * 8);
    #pragma unroll
    for (int t = 0; t < 8; ++t) {
      short8 b = *reinterpret_cast<const short8*>(&Wt[t * 16 + m][ks * 32 + quad * 8]);
      acc[t] = __builtin_amdgcn_mfma_f32_16x16x32_bf16(a, b, acc[t], 0, 0, 0);
    }
  }
  int orow0 = blockIdx.x * 64 + w * 16 + quad * 4;
  #pragma unroll
  for (int t = 0; t < 8; ++t) {
    #pragma unroll
    for (int r = 0; r < 4; ++r) {
      O[(size_t)(orow0 + r) * DD + t * 16 + m] = f2bf(acc[t][r]);
    }
  }
}

// h = gelu(h + msg @ Wo[layer]); writes fp32 h (in place) + bf16 copy
__global__ __launch_bounds__(256) void k_gemm_o(const unsigned short* A,
    const void* Wo, const int* mode, int layer, float* h, unsigned short* hbf) {
  __shared__ unsigned short Wt[DD][136];
  bool fm = mode[0] != 0;
  const void* W = fm ? (const void*)((const float*)Wo + (size_t)layer * DD * DD)
                     : (const void*)((const unsigned short*)Wo + (size_t)layer * DD * DD);
  int tid = threadIdx.x;
  stage_w(W, fm, tid, Wt);
  __syncthreads();
  int w = tid >> 6, lane = tid & 63;
  int m = lane & 15, quad = lane >> 4;
  int row = blockIdx.x * 64 + w * 16 + m;
  floatx4 acc[8];
  #pragma unroll
  for (int t = 0; t < 8; ++t) acc[t] = (floatx4){0.f, 0.f, 0.f, 0.f};
  const unsigned short* arow = A + (size_t)row * DD;
  #pragma unroll
  for (int ks = 0; ks < 4; ++ks) {
    short8 a = *reinterpret_cast<const short8*>(arow + ks * 32 + quad * 8);
    #pragma unroll
    for (int t = 0; t < 8; ++t) {
      short8 b = *reinterpret_cast<const short8*>(&Wt[t * 16 + m][ks * 32 + quad * 8]);
      acc[t] = __builtin_amdgcn_mfma_f32_16x16x32_bf16(a, b, acc[t], 0, 0, 0);
    }
  }
  int orow0 = blockIdx.x * 64 + w * 16 + quad * 4;
  #pragma unroll
  for (int t = 0; t < 8; ++t) {
    #pragma unroll
    for (int r = 0; r < 4; ++r) {
      size_t o = (size_t)(orow0 + r) * DD + t * 16 + m;
      float xv = acc[t][r] + h[o];
      float gl = 0.5f * xv * (1.f + tanhf(0.7978845608028654f * (xv + 0.044715f * xv * xv * xv)));
      h[o] = gl;
      hbf[o] = f2bf(gl);
    }
  }
}

// one wave per dst node: exact segment softmax (shift-invariant; scores are tiny) + weighted V
__global__ __launch_bounds__(256) void k_attn(const unsigned short* Q, const unsigned short* K,
    const unsigned short* V, const float* relk, const float* relv, const float* pris,
    const int* ei, const int* ea, const int* deg, const int* bucket, int layer,
    unsigned short* msgb) {
  int w = threadIdx.x >> 6, lane = threadIdx.x & 63;
  int dst = blockIdx.x * 4 + w;
  const float* rk = relk + (size_t)layer * NRC * DD;
  const float* rv = relv + (size_t)layer * NRC * DD;
  unsigned int qu = ((const unsigned int*)Q)[(size_t)dst * 64 + lane];
  float q0 = bf2f((unsigned short)(qu & 0xffffu));
  float q1 = bf2f((unsigned short)(qu >> 16));
  float den = 0.f, m0 = 0.f, m1 = 0.f;
  int dg = deg[dst]; if (dg > 64) dg = 64;
  for (int i = 0; i < dg; ++i) {
    int e = bucket[dst * 64 + i];
    int src = ei[e];
    int r = ea[e];
    unsigned int ku = ((const unsigned int*)K)[(size_t)src * 64 + lane];
    float2 rkk = ((const float2*)(rk + (size_t)r * DD))[lane];
    float t = q0 * (bf2f((unsigned short)(ku & 0xffffu)) + rkk.x)
            + q1 * (bf2f((unsigned short)(ku >> 16)) + rkk.y);
    // reduce over 16-lane head group (lane pairs hold 2 elems; head = lane/16)
    t += __shfl_xor(t, 1); t += __shfl_xor(t, 2);
    t += __shfl_xor(t, 4); t += __shfl_xor(t, 8);
    float ex = __expf(t * pris[r]);
    unsigned int vu = ((const unsigned int*)V)[(size_t)src * 64 + lane];
    float2 rvv = ((const float2*)(rv + (size_t)r * DD))[lane];
    den += ex;
    m0 += ex * (bf2f((unsigned short)(vu & 0xffffu)) + rvv.x);
    m1 += ex * (bf2f((unsigned short)(vu >> 16)) + rvv.y);
  }
  float inv = 1.f / (den + 1e-16f);
  unsigned int o = ((unsigned int)f2bf(m1 * inv) << 16) | (unsigned int)f2bf(m0 * inv);
  ((unsigned int*)msgb)[(size_t)dst * 64 + lane] = o;
}

// emb[b] = h[excl_cumsum(s)[b] + y[b]]
__global__ void k_extract(const float* h, const int* y, const int* s, float* emb) {
  int b = blockIdx.x, d = threadIdx.x;
  int offn = 0;
  for (int j = 0; j < b; ++j) offn += s[j];
  int idx = offn + y[b];
  emb[(size_t)b * DD + d] = h[(size_t)idx * DD + d];
}

// loss = mean_{i,j} max(0, pos_i - neg_j + 1); output dtype follows detected mode
__global__ __launch_bounds__(256) void k_loss(const float* eh, const float* et, const float* en,
    const void* rel, const int* sample, const int* mode, void* out) {
  __shared__ float pos[BBATCH], neg[BBATCH], wsum[4];
  bool fm = mode[0] != 0;
  int b = threadIdx.x;
  int r = sample[b * 3 + 1];
  float ap = 0.f, an = 0.f;
  for (int d = 0; d < DD; ++d) {
    float tt = et[b * DD + d];
    float rr = fm ? ((const float*)rel)[r * DD + d] : bf2f(((const unsigned short*)rel)[r * DD + d]);
    float dp = tt - (eh[b * DD + d] + rr) + 1e-8f;
    float dn = tt - en[b * DD + d] + 1e-8f;
    ap += dp * dp; an += dn * dn;
  }
  pos[b] = sqrtf(ap); neg[b] = sqrtf(an);
  __syncthreads();
  float pb = pos[b];
  float local = 0.f;
  for (int j = 0; j < BBATCH; ++j) {
    float v = pb - neg[j] + 1.0f;
    local += v > 0.f ? v : 0.f;
  }
  for (int o2 = 32; o2 > 0; o2 >>= 1) local += __shfl_down(local, o2);
  if ((b & 63) == 0) wsum[b >> 6] = local;
  __syncthreads();
  if (b == 0) {
    float loss = (wsum[0] + wsum[1] + wsum[2] + wsum[3]) * (1.f / (256.f * 256.f));
    if (fm) ((float*)out)[0] = loss;
    else    ((unsigned short*)out)[0] = f2bf(loss);
  }
}

extern "C" void kernel_launch(void* const* d_in, const int* in_sizes, int n_in,
                              void* d_out, int out_size, void* d_ws, size_t ws_size,
                              hipStream_t stream) {
  const void* ent   = d_in[0];
  const void* rel   = d_in[1];
  const void* prior = d_in[2];
  const void* Wq  = d_in[3];
  const void* Wk  = d_in[4];
  const void* Wv  = d_in[5];
  const void* Wo  = d_in[6];
  const void* Wek = d_in[7];
  const void* Wev = d_in[8];
  const int* sample = (const int*)d_in[24];

  size_t off = 0;
  char* basep = (char*)d_ws;
  auto alloc = [&](size_t bytes) -> void* {
    void* r = basep + off;
    off = (off + bytes + 255) & ~(size_t)255;
    return r;
  };
  float*          h    = (float*)alloc((size_t)NNODE * DD * 4);
  unsigned short* hbf  = (unsigned short*)alloc((size_t)NNODE * DD * 2);
  unsigned short* Qb   = (unsigned short*)alloc((size_t)NNODE * DD * 2);
  unsigned short* Kb   = (unsigned short*)alloc((size_t)NNODE * DD * 2);
  unsigned short* Vb   = (unsigned short*)alloc((size_t)NNODE * DD * 2);
  unsigned short* msgb = (unsigned short*)alloc((size_t)NNODE * DD * 2);
  float* relk = (float*)alloc((size_t)LLC * NRC * DD * 4);
  float* relv = (float*)alloc((size_t)LLC * NRC * DD * 4);
  float* pris = (float*)alloc((size_t)NRC * 4);
  int*   deg  = (int*)alloc((size_t)NNODE * 4);
  int*   bucket = (int*)alloc((size_t)NNODE * 64 * 4);
  float* emb  = (float*)alloc((size_t)3 * BBATCH * DD * 4);
  int*   mode = (int*)alloc(256);

  k_detect<<<1, 256, 0, stream>>>((const unsigned int*)ent, mode);
  k_pri<<<2, 256, 0, stream>>>(prior, mode, pris);
  k_rel<<<dim3(NRC, LLC, 2), DD, 0, stream>>>(rel, Wek, Wev, mode, relk, relv);

  for (int g = 0; g < 3; ++g) {
    const int* x  = (const int*)d_in[9 + 5 * g];
    const int* ei = (const int*)d_in[10 + 5 * g];
    const int* ea = (const int*)d_in[11 + 5 * g];
    const int* y  = (const int*)d_in[12 + 5 * g];
    const int* s  = (const int*)d_in[13 + 5 * g];
    hipMemsetAsync(deg, 0, (size_t)NNODE * 4, stream);
    k_gather<<<NNODE * 64 / 256, 256, 0, stream>>>(ent, x, mode, h, hbf);
    k_bucket<<<EEDGE / 256, 256, 0, stream>>>(ei, deg, bucket);
    for (int l = 0; l < LLC; ++l) {
      k_gemm_qkv<<<dim3(NNODE / 64, 3), 256, 0, stream>>>(hbf, Wq, Wk, Wv, mode, l, Qb, Kb, Vb);
      k_attn<<<NNODE / 4, 256, 0, stream>>>(Qb, Kb, Vb, relk, relv, pris, ei, ea, deg, bucket, l, msgb);
      k_gemm_o<<<NNODE / 64, 256, 0, stream>>>(msgb, Wo, mode, l, h, hbf);
    }
    k_extract<<<BBATCH, DD, 0, stream>>>(h, y, s, emb + (size_t)g * BBATCH * DD);
  }
  k_loss<<<1, BBATCH, 0, stream>>>(emb, emb + BBATCH * DD, emb + 2 * BBATCH * DD,
                                   rel, sample, mode, d_out);
}

// Round 4
// 848.286 us; speedup vs baseline: 1.2197x; 1.2197x over previous
//
#include <hip/hip_runtime.h>
#include <hip/hip_bf16.h>
#include <math.h>

#define NEC 200000
#define NRC 500
#define DD 128
#define LLC 2
#define NNODE 32768
#define EEDGE 262144
#define BBATCH 256

typedef __attribute__((ext_vector_type(8))) short short8;
typedef __attribute__((ext_vector_type(4))) float floatx4;
typedef __attribute__((ext_vector_type(4))) unsigned short ushort4v;

__device__ __forceinline__ float bf2f(unsigned short u) {
  union { unsigned int i; float f; } c; c.i = ((unsigned int)u) << 16; return c.f;
}
__device__ __forceinline__ unsigned short f2bf(float f) {
  union { float f; unsigned int i; } c; c.f = f;
  unsigned int x = c.i;
  unsigned int r = x + 0x7fffu + ((x >> 16) & 1u);
  return (unsigned short)(r >> 16);
}

// Detect input storage dtype (fp32 vs bf16); mode=1 -> fp32. See round-2 notes.
__global__ void k_detect(const unsigned int* ent_u32, int* mode) {
  int t = threadIdx.x;
  float best = 0.f;
  for (int i = 0; i < 16; ++i) {
    unsigned int w = ent_u32[t * 16 + i];
    float lo = fabsf(bf2f((unsigned short)(w & 0xffffu)));
    if (lo > best) best = lo;
  }
  for (int o = 32; o > 0; o >>= 1) {
    float n = __shfl_down(best, o);
    if (n > best) best = n;
  }
  __shared__ float wmax[4];
  if ((t & 63) == 0) wmax[t >> 6] = best;
  __syncthreads();
  if (t == 0) {
    float m = fmaxf(fmaxf(wmax[0], wmax[1]), fmaxf(wmax[2], wmax[3]));
    mode[0] = (m > 100.f) ? 1 : 0;
  }
}

__global__ void k_pri(const void* prior, const int* mode, float* pris) {
  int r = blockIdx.x * 256 + threadIdx.x;
  if (r >= NRC) return;
  float p = mode[0] ? ((const float*)prior)[r] : bf2f(((const unsigned short*)prior)[r]);
  pris[r] = p * 0.17677669529663687f; // 1/sqrt(32)
}

// rel tables in bf16 now (halves attn traffic; error budget is ~30x slack)
__global__ void k_rel(const void* rel, const void* Wek, const void* Wev,
                      const int* mode, unsigned short* relk, unsigned short* relv) {
  int r = blockIdx.x, l = blockIdx.y, which = blockIdx.z;
  int d = threadIdx.x;
  bool fm = mode[0] != 0;
  size_t wofs = (size_t)l * DD * DD;
  const float* Wf = (const float*)(which ? Wev : Wek) + wofs;
  const unsigned short* Wb = (const unsigned short*)(which ? Wev : Wek) + wofs;
  __shared__ float re[DD];
  re[d] = fm ? ((const float*)rel)[r * DD + d] : bf2f(((const unsigned short*)rel)[r * DD + d]);
  __syncthreads();
  float acc = 0.f;
  if (fm) { for (int c = 0; c < DD; ++c) acc += re[c] * Wf[c * DD + d]; }
  else    { for (int c = 0; c < DD; ++c) acc += re[c] * bf2f(Wb[c * DD + d]); }
  unsigned short* out = which ? relv : relk;
  out[((size_t)l * NRC + r) * DD + d] = f2bf(acc);
}

__global__ void k_gather(const void* ent, const int* x, const int* mode,
                         float* h, unsigned short* hbf) {
  int t = blockIdx.x * 256 + threadIdx.x;
  int n = t >> 6, p = t & 63;
  int row = x[n];
  float2 f;
  if (mode[0]) {
    f = ((const float2*)((const float*)ent + (size_t)row * DD))[p];
  } else {
    unsigned int v = ((const unsigned int*)((const unsigned short*)ent + (size_t)row * DD))[p];
    f.x = bf2f((unsigned short)(v & 0xffffu));
    f.y = bf2f((unsigned short)(v >> 16));
  }
  ((unsigned int*)hbf)[t] = ((unsigned int)f2bf(f.y) << 16) | (unsigned int)f2bf(f.x);
  ((float2*)h)[t] = f;
}

// bucket entry packs src (15 bits) | rel (<<15): kills 2 serial load levels in attn
__global__ void k_bucket(const int* ei, const int* ea, int* deg, unsigned int* bucket) {
  int e = blockIdx.x * 256 + threadIdx.x;
  if (e >= EEDGE) return;
  int dst = ei[EEDGE + e];
  int src = ei[e];
  int r = ea[e];
  int pos = atomicAdd(&deg[dst], 1);
  if (pos < 64) bucket[dst * 64 + pos] = (unsigned int)src | ((unsigned int)r << 15);
}

__device__ __forceinline__ void stage_w(const void* W, bool fm, int tid,
                                        unsigned short (*Wt)[136]) {
  const float* Wf = (const float*)W;
  const unsigned short* Wb = (const unsigned short*)W;
  for (int pass = 0; pass < 8; ++pass) {
    int idx = pass * 256 + tid;
    int c = idx >> 4;
    int d0 = (idx & 15) << 3;
    if (fm) {
      #pragma unroll
      for (int j = 0; j < 8; ++j) Wt[d0 + j][c] = f2bf(Wf[c * DD + d0 + j]);
    } else {
      short8 v = *reinterpret_cast<const short8*>(Wb + c * DD + d0);
      #pragma unroll
      for (int j = 0; j < 8; ++j) Wt[d0 + j][c] = (unsigned short)v[j];
    }
  }
}

// Q/K/V GEMM; epilogue now LDS-repacks to coalesced b128 stores
__global__ __launch_bounds__(256) void k_gemm_qkv(const unsigned short* A,
    const void* Wq, const void* Wk, const void* Wv, const int* mode,
    int layer, unsigned short* Qo, unsigned short* Ko, unsigned short* Vo) {
  __shared__ unsigned short Wt[DD][136];
  const void* W; unsigned short* O;
  if (blockIdx.y == 0)      { W = Wq; O = Qo; }
  else if (blockIdx.y == 1) { W = Wk; O = Ko; }
  else                      { W = Wv; O = Vo; }
  bool fm = mode[0] != 0;
  W = fm ? (const void*)((const float*)W + (size_t)layer * DD * DD)
         : (const void*)((const unsigned short*)W + (size_t)layer * DD * DD);
  int tid = threadIdx.x;
  stage_w(W, fm, tid, Wt);
  __syncthreads();
  int w = tid >> 6, lane = tid & 63;
  int m = lane & 15, quad = lane >> 4;
  int row = blockIdx.x * 64 + w * 16 + m;
  floatx4 acc[8];
  #pragma unroll
  for (int t = 0; t < 8; ++t) acc[t] = (floatx4){0.f, 0.f, 0.f, 0.f};
  const unsigned short* arow = A + (size_t)row * DD;
  #pragma unroll
  for (int ks = 0; ks < 4; ++ks) {
    short8 a = *reinterpret_cast<const short8*>(arow + ks * 32 + quad * 8);
    #pragma unroll
    for (int t = 0; t < 8; ++t) {
      short8 b = *reinterpret_cast<const short8*>(&Wt[t * 16 + m][ks * 32 + quad * 8]);
      acc[t] = __builtin_amdgcn_mfma_f32_16x16x32_bf16(a, b, acc[t], 0, 0, 0);
    }
  }
  // epilogue: acc -> LDS (reuse Wt) -> coalesced vector stores
  __syncthreads();
  unsigned short* ut = &Wt[0][0]; // stride 136 u16, rows 0..63
  #pragma unroll
  for (int t = 0; t < 8; ++t) {
    #pragma unroll
    for (int r = 0; r < 4; ++r) {
      ut[(w * 16 + quad * 4 + r) * 136 + t * 16 + m] = f2bf(acc[t][r]);
    }
  }
  __syncthreads();
  int rowbase = blockIdx.x * 64;
  #pragma unroll
  for (int k = 0; k < 4; ++k) {
    int flat = k * 256 + tid;      // 1024 chunks of 8 u16 (16 B)
    int rw = flat >> 4, c8 = flat & 15;
    short8 v = *reinterpret_cast<const short8*>(ut + rw * 136 + c8 * 8);
    *reinterpret_cast<short8*>(O + (size_t)(rowbase + rw) * DD + c8 * 8) = v;
  }
}

// h = gelu(h + msg @ Wo); LDS-repacked epilogue with coalesced float4 h I/O
__global__ __launch_bounds__(256) void k_gemm_o(const unsigned short* A,
    const void* Wo, const int* mode, int layer, float* h, unsigned short* hbf) {
  __shared__ unsigned short Wt[DD][136];
  bool fm = mode[0] != 0;
  const void* W = fm ? (const void*)((const float*)Wo + (size_t)layer * DD * DD)
                     : (const void*)((const unsigned short*)Wo + (size_t)layer * DD * DD);
  int tid = threadIdx.x;
  stage_w(W, fm, tid, Wt);
  __syncthreads();
  int w = tid >> 6, lane = tid & 63;
  int m = lane & 15, quad = lane >> 4;
  int row = blockIdx.x * 64 + w * 16 + m;
  floatx4 acc[8];
  #pragma unroll
  for (int t = 0; t < 8; ++t) acc[t] = (floatx4){0.f, 0.f, 0.f, 0.f};
  const unsigned short* arow = A + (size_t)row * DD;
  #pragma unroll
  for (int ks = 0; ks < 4; ++ks) {
    short8 a = *reinterpret_cast<const short8*>(arow + ks * 32 + quad * 8);
    #pragma unroll
    for (int t = 0; t < 8; ++t) {
      short8 b = *reinterpret_cast<const short8*>(&Wt[t * 16 + m][ks * 32 + quad * 8]);
      acc[t] = __builtin_amdgcn_mfma_f32_16x16x32_bf16(a, b, acc[t], 0, 0, 0);
    }
  }
  __syncthreads();
  float* ft = (float*)&Wt[0][0]; // 64 rows x stride 136 f32 = 34816 B (exact Wt size)
  #pragma unroll
  for (int t = 0; t < 8; ++t) {
    #pragma unroll
    for (int r = 0; r < 4; ++r) {
      ft[(w * 16 + quad * 4 + r) * 136 + t * 16 + m] = acc[t][r];
    }
  }
  __syncthreads();
  int rowbase = blockIdx.x * 64;
  #pragma unroll
  for (int k = 0; k < 8; ++k) {
    int flat = k * 256 + tid;      // 2048 chunks of 4 f32 (16 B)
    int rw = flat >> 5, c4 = flat & 31;
    float4 v = *reinterpret_cast<const float4*>(ft + rw * 136 + c4 * 4);
    size_t gi = (size_t)(rowbase + rw) * DD + c4 * 4;
    float4 hv = *reinterpret_cast<const float4*>(h + gi);
    float4 res;
    {
      float xv = v.x + hv.x;
      res.x = 0.5f * xv * (1.f + tanhf(0.7978845608028654f * (xv + 0.044715f * xv * xv * xv)));
      xv = v.y + hv.y;
      res.y = 0.5f * xv * (1.f + tanhf(0.7978845608028654f * (xv + 0.044715f * xv * xv * xv)));
      xv = v.z + hv.z;
      res.z = 0.5f * xv * (1.f + tanhf(0.7978845608028654f * (xv + 0.044715f * xv * xv * xv)));
      xv = v.w + hv.w;
      res.w = 0.5f * xv * (1.f + tanhf(0.7978845608028654f * (xv + 0.044715f * xv * xv * xv)));
    }
    *reinterpret_cast<float4*>(h + gi) = res;
    ushort4v b4 = { f2bf(res.x), f2bf(res.y), f2bf(res.z), f2bf(res.w) };
    *reinterpret_cast<ushort4v*>(hbf + gi) = b4;
  }
}

// one wave per dst node; packed bucket entries + prefetch; bf16 rel tables
__global__ __launch_bounds__(256) void k_attn(const unsigned short* Q, const unsigned short* K,
    const unsigned short* V, const unsigned short* relk, const unsigned short* relv,
    const float* pris, const int* deg, const unsigned int* bucket, int layer,
    unsigned short* msgb) {
  int w = threadIdx.x >> 6, lane = threadIdx.x & 63;
  int dst = blockIdx.x * 4 + w;
  const unsigned int* rk32 = (const unsigned int*)(relk + (size_t)layer * NRC * DD);
  const unsigned int* rv32 = (const unsigned int*)(relv + (size_t)layer * NRC * DD);
  const unsigned int* K32 = (const unsigned int*)K;
  const unsigned int* V32 = (const unsigned int*)V;
  unsigned int qu = ((const unsigned int*)Q)[(size_t)dst * 64 + lane];
  float q0 = bf2f((unsigned short)(qu & 0xffffu));
  float q1 = bf2f((unsigned short)(qu >> 16));
  float den = 0.f, m0 = 0.f, m1 = 0.f;
  int dg = deg[dst]; if (dg > 64) dg = 64;
  int base = dst * 64;
  unsigned int pe = bucket[base]; // prefetch (unused if dg==0; memory always valid)
  for (int i = 0; i < dg; ++i) {
    unsigned int cur = pe;
    int nx = (i + 1 < dg) ? i + 1 : i;
    pe = bucket[base + nx];
    int src = (int)(cur & 32767u);
    int r = (int)(cur >> 15);
    unsigned int ku = K32[src * 64 + lane];
    unsigned int rk2 = rk32[r * 64 + lane];
    unsigned int vu = V32[src * 64 + lane];
    unsigned int rv2 = rv32[r * 64 + lane];
    float p = pris[r];
    float t = q0 * (bf2f((unsigned short)(ku & 0xffffu)) + bf2f((unsigned short)(rk2 & 0xffffu)))
            + q1 * (bf2f((unsigned short)(ku >> 16)) + bf2f((unsigned short)(rk2 >> 16)));
    t += __shfl_xor(t, 1); t += __shfl_xor(t, 2);
    t += __shfl_xor(t, 4); t += __shfl_xor(t, 8);
    float ex = __expf(t * p);
    den += ex;
    m0 += ex * (bf2f((unsigned short)(vu & 0xffffu)) + bf2f((unsigned short)(rv2 & 0xffffu)));
    m1 += ex * (bf2f((unsigned short)(vu >> 16)) + bf2f((unsigned short)(rv2 >> 16)));
  }
  float inv = 1.f / (den + 1e-16f);
  unsigned int o = ((unsigned int)f2bf(m1 * inv) << 16) | (unsigned int)f2bf(m0 * inv);
  ((unsigned int*)msgb)[(size_t)dst * 64 + lane] = o;
}

__global__ void k_extract(const float* h, const int* y, const int* s, float* emb) {
  int b = blockIdx.x, d = threadIdx.x;
  int offn = 0;
  for (int j = 0; j < b; ++j) offn += s[j];
  int idx = offn + y[b];
  emb[(size_t)b * DD + d] = h[(size_t)idx * DD + d];
}

// parallel pos/neg: one block per b (128 threads)
__global__ void k_posneg(const float* eh, const float* et, const float* en,
    const void* rel, const int* sample, const int* mode, float* pos, float* neg) {
  int b = blockIdx.x, d = threadIdx.x;
  bool fm = mode[0] != 0;
  int r = sample[b * 3 + 1];
  float tt = et[b * DD + d];
  float rr = fm ? ((const float*)rel)[r * DD + d] : bf2f(((const unsigned short*)rel)[r * DD + d]);
  float dp = tt - (eh[b * DD + d] + rr) + 1e-8f;
  float dn = tt - en[b * DD + d] + 1e-8f;
  float ap = dp * dp, an = dn * dn;
  for (int o = 32; o > 0; o >>= 1) { ap += __shfl_down(ap, o); an += __shfl_down(an, o); }
  __shared__ float sa[2], sb[2];
  if ((d & 63) == 0) { sa[d >> 6] = ap; sb[d >> 6] = an; }
  __syncthreads();
  if (d == 0) { pos[b] = sqrtf(sa[0] + sa[1]); neg[b] = sqrtf(sb[0] + sb[1]); }
}

__global__ __launch_bounds__(256) void k_hinge(const float* pos, const float* neg,
    const int* mode, void* out) {
  __shared__ float ns[BBATCH];
  __shared__ float wsum[4];
  int t = threadIdx.x;
  ns[t] = neg[t];
  float pb = pos[t];
  __syncthreads();
  float local = 0.f;
  for (int j = 0; j < BBATCH; ++j) {
    float v = pb - ns[j] + 1.0f;
    local += v > 0.f ? v : 0.f;
  }
  for (int o = 32; o > 0; o >>= 1) local += __shfl_down(local, o);
  if ((t & 63) == 0) wsum[t >> 6] = local;
  __syncthreads();
  if (t == 0) {
    float loss = (wsum[0] + wsum[1] + wsum[2] + wsum[3]) * (1.f / (256.f * 256.f));
    if (mode[0]) ((float*)out)[0] = loss;
    else         ((unsigned short*)out)[0] = f2bf(loss);
  }
}

extern "C" void kernel_launch(void* const* d_in, const int* in_sizes, int n_in,
                              void* d_out, int out_size, void* d_ws, size_t ws_size,
                              hipStream_t stream) {
  const void* ent   = d_in[0];
  const void* rel   = d_in[1];
  const void* prior = d_in[2];
  const void* Wq  = d_in[3];
  const void* Wk  = d_in[4];
  const void* Wv  = d_in[5];
  const void* Wo  = d_in[6];
  const void* Wek = d_in[7];
  const void* Wev = d_in[8];
  const int* sample = (const int*)d_in[24];

  size_t off = 0;
  char* basep = (char*)d_ws;
  auto alloc = [&](size_t bytes) -> void* {
    void* r = basep + off;
    off = (off + bytes + 255) & ~(size_t)255;
    return r;
  };
  float*          h    = (float*)alloc((size_t)NNODE * DD * 4);
  unsigned short* hbf  = (unsigned short*)alloc((size_t)NNODE * DD * 2);
  unsigned short* Qb   = (unsigned short*)alloc((size_t)NNODE * DD * 2);
  unsigned short* Kb   = (unsigned short*)alloc((size_t)NNODE * DD * 2);
  unsigned short* Vb   = (unsigned short*)alloc((size_t)NNODE * DD * 2);
  unsigned short* msgb = (unsigned short*)alloc((size_t)NNODE * DD * 2);
  unsigned short* relk = (unsigned short*)alloc((size_t)LLC * NRC * DD * 2);
  unsigned short* relv = (unsigned short*)alloc((size_t)LLC * NRC * DD * 2);
  float* pris = (float*)alloc((size_t)NRC * 4);
  int*   deg  = (int*)alloc((size_t)NNODE * 4);
  unsigned int* bucket = (unsigned int*)alloc((size_t)NNODE * 64 * 4);
  float* emb  = (float*)alloc((size_t)3 * BBATCH * DD * 4);
  float* pos  = (float*)alloc((size_t)BBATCH * 4);
  float* neg  = (float*)alloc((size_t)BBATCH * 4);
  int*   mode = (int*)alloc(256);

  k_detect<<<1, 256, 0, stream>>>((const unsigned int*)ent, mode);
  k_pri<<<2, 256, 0, stream>>>(prior, mode, pris);
  k_rel<<<dim3(NRC, LLC, 2), DD, 0, stream>>>(rel, Wek, Wev, mode, relk, relv);

  for (int g = 0; g < 3; ++g) {
    const int* x  = (const int*)d_in[9 + 5 * g];
    const int* ei = (const int*)d_in[10 + 5 * g];
    const int* ea = (const int*)d_in[11 + 5 * g];
    const int* y  = (const int*)d_in[12 + 5 * g];
    const int* s  = (const int*)d_in[13 + 5 * g];
    hipMemsetAsync(deg, 0, (size_t)NNODE * 4, stream);
    k_gather<<<NNODE * 64 / 256, 256, 0, stream>>>(ent, x, mode, h, hbf);
    k_bucket<<<EEDGE / 256, 256, 0, stream>>>(ei, ea, deg, bucket);
    for (int l = 0; l < LLC; ++l) {
      k_gemm_qkv<<<dim3(NNODE / 64, 3), 256, 0, stream>>>(hbf, Wq, Wk, Wv, mode, l, Qb, Kb, Vb);
      k_attn<<<NNODE / 4, 256, 0, stream>>>(Qb, Kb, Vb, relk, relv, pris, deg, bucket, l, msgb);
      k_gemm_o<<<NNODE / 64, 256, 0, stream>>>(msgb, Wo, mode, l, h, hbf);
    }
    k_extract<<<BBATCH, DD, 0, stream>>>(h, y, s, emb + (size_t)g * BBATCH * DD);
  }
  k_posneg<<<BBATCH, DD, 0, stream>>>(emb, emb + BBATCH * DD, emb + 2 * BBATCH * DD,
                                      rel, sample, mode, pos, neg);
  k_hinge<<<1, BBATCH, 0, stream>>>(pos, neg, mode, d_out);
}

// Round 5
// 741.365 us; speedup vs baseline: 1.3956x; 1.1442x over previous
//
#include <hip/hip_runtime.h>
#include <hip/hip_bf16.h>
#include <math.h>

#define NEC 200000
#define NRC 500
#define DD 128
#define LLC 2
#define NNODE 32768
#define EEDGE 262144
#define BBATCH 256
#define NG 3

typedef __attribute__((ext_vector_type(8))) short short8;
typedef __attribute__((ext_vector_type(4))) float floatx4;
typedef __attribute__((ext_vector_type(4))) unsigned short ushort4v;

__device__ __forceinline__ float bf2f(unsigned short u) {
  union { unsigned int i; float f; } c; c.i = ((unsigned int)u) << 16; return c.f;
}
__device__ __forceinline__ unsigned short f2bf(float f) {
  union { float f; unsigned int i; } c; c.f = f;
  unsigned int x = c.i;
  unsigned int r = x + 0x7fffu + ((x >> 16) & 1u);
  return (unsigned short)(r >> 16);
}

// Detect input storage dtype (fp32 vs bf16); mode=1 -> fp32.
__global__ void k_detect(const unsigned int* ent_u32, int* mode) {
  int t = threadIdx.x;
  float best = 0.f;
  for (int i = 0; i < 16; ++i) {
    unsigned int w = ent_u32[t * 16 + i];
    float lo = fabsf(bf2f((unsigned short)(w & 0xffffu)));
    if (lo > best) best = lo;
  }
  for (int o = 32; o > 0; o >>= 1) {
    float n = __shfl_down(best, o);
    if (n > best) best = n;
  }
  __shared__ float wmax[4];
  if ((t & 63) == 0) wmax[t >> 6] = best;
  __syncthreads();
  if (t == 0) {
    float m = fmaxf(fmaxf(wmax[0], wmax[1]), fmaxf(wmax[2], wmax[3]));
    mode[0] = (m > 100.f) ? 1 : 0;
  }
}

__global__ void k_pri(const void* prior, const int* mode, float* pris) {
  int r = blockIdx.x * 256 + threadIdx.x;
  if (r >= NRC) return;
  float p = mode[0] ? ((const float*)prior)[r] : bf2f(((const unsigned short*)prior)[r]);
  pris[r] = p * 0.17677669529663687f; // 1/sqrt(32)
}

// rel tables in bf16 (halves attn traffic)
__global__ void k_rel(const void* rel, const void* Wek, const void* Wev,
                      const int* mode, unsigned short* relk, unsigned short* relv) {
  int r = blockIdx.x, l = blockIdx.y, which = blockIdx.z;
  int d = threadIdx.x;
  bool fm = mode[0] != 0;
  size_t wofs = (size_t)l * DD * DD;
  const float* Wf = (const float*)(which ? Wev : Wek) + wofs;
  const unsigned short* Wb = (const unsigned short*)(which ? Wev : Wek) + wofs;
  __shared__ float re[DD];
  re[d] = fm ? ((const float*)rel)[r * DD + d] : bf2f(((const unsigned short*)rel)[r * DD + d]);
  __syncthreads();
  float acc = 0.f;
  if (fm) { for (int c = 0; c < DD; ++c) acc += re[c] * Wf[c * DD + d]; }
  else    { for (int c = 0; c < DD; ++c) acc += re[c] * bf2f(Wb[c * DD + d]); }
  unsigned short* out = which ? relv : relk;
  out[((size_t)l * NRC + r) * DD + d] = f2bf(acc);
}

// batched over graphs: blockIdx.y = graph
__global__ void k_gather(const void* ent, const int* x0, const int* x1, const int* x2,
                         const int* mode, float* h, unsigned short* hbf) {
  int g = blockIdx.y;
  const int* x = g == 0 ? x0 : (g == 1 ? x1 : x2);
  int t = blockIdx.x * 256 + threadIdx.x;   // 0..NN*64-1 within graph
  int n = t >> 6, p = t & 63;
  int row = x[n];
  float2 f;
  if (mode[0]) {
    f = ((const float2*)((const float*)ent + (size_t)row * DD))[p];
  } else {
    unsigned int v = ((const unsigned int*)((const unsigned short*)ent + (size_t)row * DD))[p];
    f.x = bf2f((unsigned short)(v & 0xffffu));
    f.y = bf2f((unsigned short)(v >> 16));
  }
  size_t gi = (size_t)g * NNODE * 64 + t;   // in 2-elem units
  ((unsigned int*)hbf)[gi] = ((unsigned int)f2bf(f.y) << 16) | (unsigned int)f2bf(f.x);
  ((float2*)h)[gi] = f;
}

// bucket entry packs src (15 bits) | rel (<<15); batched over graphs
__global__ void k_bucket(const int* ei0, const int* ea0, const int* ei1, const int* ea1,
                         const int* ei2, const int* ea2, int* deg, unsigned int* bucket) {
  int g = blockIdx.y;
  const int* ei = g == 0 ? ei0 : (g == 1 ? ei1 : ei2);
  const int* ea = g == 0 ? ea0 : (g == 1 ? ea1 : ea2);
  int e = blockIdx.x * 256 + threadIdx.x;
  if (e >= EEDGE) return;
  int dst = ei[EEDGE + e];
  int src = ei[e];
  int r = ea[e];
  int pos = atomicAdd(&deg[g * NNODE + dst], 1);
  if (pos < 64) bucket[((size_t)g * NNODE + dst) * 64 + pos] = (unsigned int)src | ((unsigned int)r << 15);
}

__device__ __forceinline__ void stage_w(const void* W, bool fm, int tid,
                                        unsigned short (*Wt)[136]) {
  const float* Wf = (const float*)W;
  const unsigned short* Wb = (const unsigned short*)W;
  for (int pass = 0; pass < 8; ++pass) {
    int idx = pass * 256 + tid;
    int c = idx >> 4;
    int d0 = (idx & 15) << 3;
    if (fm) {
      #pragma unroll
      for (int j = 0; j < 8; ++j) Wt[d0 + j][c] = f2bf(Wf[c * DD + d0 + j]);
    } else {
      short8 v = *reinterpret_cast<const short8*>(Wb + c * DD + d0);
      #pragma unroll
      for (int j = 0; j < 8; ++j) Wt[d0 + j][c] = (unsigned short)v[j];
    }
  }
}

// Q/K/V GEMM batched: grid (512, 3=which, 3=graph)
__global__ __launch_bounds__(256) void k_gemm_qkv(const unsigned short* A,
    const void* Wq, const void* Wk, const void* Wv, const int* mode,
    int layer, unsigned short* Qo, unsigned short* Ko, unsigned short* Vo) {
  __shared__ unsigned short Wt[DD][136];
  const void* W; unsigned short* O;
  if (blockIdx.y == 0)      { W = Wq; O = Qo; }
  else if (blockIdx.y == 1) { W = Wk; O = Ko; }
  else                      { W = Wv; O = Vo; }
  int g = blockIdx.z;
  const unsigned short* Ag = A + (size_t)g * NNODE * DD;
  unsigned short* Og = O + (size_t)g * NNODE * DD;
  bool fm = mode[0] != 0;
  W = fm ? (const void*)((const float*)W + (size_t)layer * DD * DD)
         : (const void*)((const unsigned short*)W + (size_t)layer * DD * DD);
  int tid = threadIdx.x;
  stage_w(W, fm, tid, Wt);
  __syncthreads();
  int w = tid >> 6, lane = tid & 63;
  int m = lane & 15, quad = lane >> 4;
  int row = blockIdx.x * 64 + w * 16 + m;
  floatx4 acc[8];
  #pragma unroll
  for (int t = 0; t < 8; ++t) acc[t] = (floatx4){0.f, 0.f, 0.f, 0.f};
  const unsigned short* arow = Ag + (size_t)row * DD;
  #pragma unroll
  for (int ks = 0; ks < 4; ++ks) {
    short8 a = *reinterpret_cast<const short8*>(arow + ks * 32 + quad * 8);
    #pragma unroll
    for (int t = 0; t < 8; ++t) {
      short8 b = *reinterpret_cast<const short8*>(&Wt[t * 16 + m][ks * 32 + quad * 8]);
      acc[t] = __builtin_amdgcn_mfma_f32_16x16x32_bf16(a, b, acc[t], 0, 0, 0);
    }
  }
  __syncthreads();
  unsigned short* ut = &Wt[0][0];
  #pragma unroll
  for (int t = 0; t < 8; ++t) {
    #pragma unroll
    for (int r = 0; r < 4; ++r) {
      ut[(w * 16 + quad * 4 + r) * 136 + t * 16 + m] = f2bf(acc[t][r]);
    }
  }
  __syncthreads();
  int rowbase = blockIdx.x * 64;
  #pragma unroll
  for (int k = 0; k < 4; ++k) {
    int flat = k * 256 + tid;
    int rw = flat >> 4, c8 = flat & 15;
    short8 v = *reinterpret_cast<const short8*>(ut + rw * 136 + c8 * 8);
    *reinterpret_cast<short8*>(Og + (size_t)(rowbase + rw) * DD + c8 * 8) = v;
  }
}

// h = gelu(h + msg @ Wo); batched: grid (512, 3=graph)
__global__ __launch_bounds__(256) void k_gemm_o(const unsigned short* A,
    const void* Wo, const int* mode, int layer, float* h, unsigned short* hbf) {
  __shared__ unsigned short Wt[DD][136];
  bool fm = mode[0] != 0;
  int g = blockIdx.y;
  const unsigned short* Ag = A + (size_t)g * NNODE * DD;
  float* hg = h + (size_t)g * NNODE * DD;
  unsigned short* hbg = hbf + (size_t)g * NNODE * DD;
  const void* W = fm ? (const void*)((const float*)Wo + (size_t)layer * DD * DD)
                     : (const void*)((const unsigned short*)Wo + (size_t)layer * DD * DD);
  int tid = threadIdx.x;
  stage_w(W, fm, tid, Wt);
  __syncthreads();
  int w = tid >> 6, lane = tid & 63;
  int m = lane & 15, quad = lane >> 4;
  int row = blockIdx.x * 64 + w * 16 + m;
  floatx4 acc[8];
  #pragma unroll
  for (int t = 0; t < 8; ++t) acc[t] = (floatx4){0.f, 0.f, 0.f, 0.f};
  const unsigned short* arow = Ag + (size_t)row * DD;
  #pragma unroll
  for (int ks = 0; ks < 4; ++ks) {
    short8 a = *reinterpret_cast<const short8*>(arow + ks * 32 + quad * 8);
    #pragma unroll
    for (int t = 0; t < 8; ++t) {
      short8 b = *reinterpret_cast<const short8*>(&Wt[t * 16 + m][ks * 32 + quad * 8]);
      acc[t] = __builtin_amdgcn_mfma_f32_16x16x32_bf16(a, b, acc[t], 0, 0, 0);
    }
  }
  __syncthreads();
  float* ft = (float*)&Wt[0][0];
  #pragma unroll
  for (int t = 0; t < 8; ++t) {
    #pragma unroll
    for (int r = 0; r < 4; ++r) {
      ft[(w * 16 + quad * 4 + r) * 136 + t * 16 + m] = acc[t][r];
    }
  }
  __syncthreads();
  int rowbase = blockIdx.x * 64;
  #pragma unroll
  for (int k = 0; k < 8; ++k) {
    int flat = k * 256 + tid;
    int rw = flat >> 5, c4 = flat & 31;
    float4 v = *reinterpret_cast<const float4*>(ft + rw * 136 + c4 * 4);
    size_t gi = (size_t)(rowbase + rw) * DD + c4 * 4;
    float4 hv = *reinterpret_cast<const float4*>(hg + gi);
    float4 res;
    {
      float xv = v.x + hv.x;
      res.x = 0.5f * xv * (1.f + tanhf(0.7978845608028654f * (xv + 0.044715f * xv * xv * xv)));
      xv = v.y + hv.y;
      res.y = 0.5f * xv * (1.f + tanhf(0.7978845608028654f * (xv + 0.044715f * xv * xv * xv)));
      xv = v.z + hv.z;
      res.z = 0.5f * xv * (1.f + tanhf(0.7978845608028654f * (xv + 0.044715f * xv * xv * xv)));
      xv = v.w + hv.w;
      res.w = 0.5f * xv * (1.f + tanhf(0.7978845608028654f * (xv + 0.044715f * xv * xv * xv)));
    }
    *reinterpret_cast<float4*>(hg + gi) = res;
    ushort4v b4 = { f2bf(res.x), f2bf(res.y), f2bf(res.z), f2bf(res.w) };
    *reinterpret_cast<ushort4v*>(hbg + gi) = b4;
  }
}

// one wave per dst node; batched: grid (8192, 3=graph)
__global__ __launch_bounds__(256) void k_attn(const unsigned short* Q, const unsigned short* K,
    const unsigned short* V, const unsigned short* relk, const unsigned short* relv,
    const float* pris, const int* deg, const unsigned int* bucket, int layer,
    unsigned short* msgb) {
  int w = threadIdx.x >> 6, lane = threadIdx.x & 63;
  int g = blockIdx.y;
  int dst = blockIdx.x * 4 + w;
  size_t gofs = (size_t)g * NNODE * 64;   // u32 units for [N][D] bf16 viewed as u32
  const unsigned int* rk32 = (const unsigned int*)(relk + (size_t)layer * NRC * DD);
  const unsigned int* rv32 = (const unsigned int*)(relv + (size_t)layer * NRC * DD);
  const unsigned int* K32 = (const unsigned int*)K + gofs;
  const unsigned int* V32 = (const unsigned int*)V + gofs;
  unsigned int qu = ((const unsigned int*)Q)[gofs + (size_t)dst * 64 + lane];
  float q0 = bf2f((unsigned short)(qu & 0xffffu));
  float q1 = bf2f((unsigned short)(qu >> 16));
  float den = 0.f, m0 = 0.f, m1 = 0.f;
  int dg = deg[g * NNODE + dst]; if (dg > 64) dg = 64;
  size_t base = ((size_t)g * NNODE + dst) * 64;
  unsigned int pe = bucket[base];
  for (int i = 0; i < dg; ++i) {
    unsigned int cur = pe;
    int nx = (i + 1 < dg) ? i + 1 : i;
    pe = bucket[base + nx];
    int src = (int)(cur & 32767u);
    int r = (int)(cur >> 15);
    unsigned int ku = K32[src * 64 + lane];
    unsigned int rk2 = rk32[r * 64 + lane];
    unsigned int vu = V32[src * 64 + lane];
    unsigned int rv2 = rv32[r * 64 + lane];
    float p = pris[r];
    float t = q0 * (bf2f((unsigned short)(ku & 0xffffu)) + bf2f((unsigned short)(rk2 & 0xffffu)))
            + q1 * (bf2f((unsigned short)(ku >> 16)) + bf2f((unsigned short)(rk2 >> 16)));
    t += __shfl_xor(t, 1); t += __shfl_xor(t, 2);
    t += __shfl_xor(t, 4); t += __shfl_xor(t, 8);
    float ex = __expf(t * p);
    den += ex;
    m0 += ex * (bf2f((unsigned short)(vu & 0xffffu)) + bf2f((unsigned short)(rv2 & 0xffffu)));
    m1 += ex * (bf2f((unsigned short)(vu >> 16)) + bf2f((unsigned short)(rv2 >> 16)));
  }
  float inv = 1.f / (den + 1e-16f);
  unsigned int o = ((unsigned int)f2bf(m1 * inv) << 16) | (unsigned int)f2bf(m0 * inv);
  ((unsigned int*)msgb)[gofs + (size_t)dst * 64 + lane] = o;
}

// batched extract: grid (256, 3)
__global__ void k_extract(const float* h, const int* y0, const int* s0,
                          const int* y1, const int* s1, const int* y2, const int* s2,
                          float* emb) {
  int g = blockIdx.y;
  const int* y = g == 0 ? y0 : (g == 1 ? y1 : y2);
  const int* s = g == 0 ? s0 : (g == 1 ? s1 : s2);
  int b = blockIdx.x, d = threadIdx.x;
  int offn = 0;
  for (int j = 0; j < b; ++j) offn += s[j];
  int idx = offn + y[b];
  emb[((size_t)g * BBATCH + b) * DD + d] = h[((size_t)g * NNODE + idx) * DD + d];
}

__global__ void k_posneg(const float* eh, const float* et, const float* en,
    const void* rel, const int* sample, const int* mode, float* pos, float* neg) {
  int b = blockIdx.x, d = threadIdx.x;
  bool fm = mode[0] != 0;
  int r = sample[b * 3 + 1];
  float tt = et[b * DD + d];
  float rr = fm ? ((const float*)rel)[r * DD + d] : bf2f(((const unsigned short*)rel)[r * DD + d]);
  float dp = tt - (eh[b * DD + d] + rr) + 1e-8f;
  float dn = tt - en[b * DD + d] + 1e-8f;
  float ap = dp * dp, an = dn * dn;
  for (int o = 32; o > 0; o >>= 1) { ap += __shfl_down(ap, o); an += __shfl_down(an, o); }
  __shared__ float sa[2], sb[2];
  if ((d & 63) == 0) { sa[d >> 6] = ap; sb[d >> 6] = an; }
  __syncthreads();
  if (d == 0) { pos[b] = sqrtf(sa[0] + sa[1]); neg[b] = sqrtf(sb[0] + sb[1]); }
}

__global__ __launch_bounds__(256) void k_hinge(const float* pos, const float* neg,
    const int* mode, void* out) {
  __shared__ float ns[BBATCH];
  __shared__ float wsum[4];
  int t = threadIdx.x;
  ns[t] = neg[t];
  float pb = pos[t];
  __syncthreads();
  float local = 0.f;
  for (int j = 0; j < BBATCH; ++j) {
    float v = pb - ns[j] + 1.0f;
    local += v > 0.f ? v : 0.f;
  }
  for (int o = 32; o > 0; o >>= 1) local += __shfl_down(local, o);
  if ((t & 63) == 0) wsum[t >> 6] = local;
  __syncthreads();
  if (t == 0) {
    float loss = (wsum[0] + wsum[1] + wsum[2] + wsum[3]) * (1.f / (256.f * 256.f));
    if (mode[0]) ((float*)out)[0] = loss;
    else         ((unsigned short*)out)[0] = f2bf(loss);
  }
}

extern "C" void kernel_launch(void* const* d_in, const int* in_sizes, int n_in,
                              void* d_out, int out_size, void* d_ws, size_t ws_size,
                              hipStream_t stream) {
  const void* ent   = d_in[0];
  const void* rel   = d_in[1];
  const void* prior = d_in[2];
  const void* Wq  = d_in[3];
  const void* Wk  = d_in[4];
  const void* Wv  = d_in[5];
  const void* Wo  = d_in[6];
  const void* Wek = d_in[7];
  const void* Wev = d_in[8];
  const int* sample = (const int*)d_in[24];

  size_t off = 0;
  char* basep = (char*)d_ws;
  auto alloc = [&](size_t bytes) -> void* {
    void* r = basep + off;
    off = (off + bytes + 255) & ~(size_t)255;
    return r;
  };
  float*          h    = (float*)alloc((size_t)NG * NNODE * DD * 4);
  unsigned short* hbf  = (unsigned short*)alloc((size_t)NG * NNODE * DD * 2);
  unsigned short* Qb   = (unsigned short*)alloc((size_t)NG * NNODE * DD * 2);
  unsigned short* Kb   = (unsigned short*)alloc((size_t)NG * NNODE * DD * 2);
  unsigned short* Vb   = (unsigned short*)alloc((size_t)NG * NNODE * DD * 2);
  unsigned short* msgb = (unsigned short*)alloc((size_t)NG * NNODE * DD * 2);
  unsigned short* relk = (unsigned short*)alloc((size_t)LLC * NRC * DD * 2);
  unsigned short* relv = (unsigned short*)alloc((size_t)LLC * NRC * DD * 2);
  float* pris = (float*)alloc((size_t)NRC * 4);
  int*   deg  = (int*)alloc((size_t)NG * NNODE * 4);
  unsigned int* bucket = (unsigned int*)alloc((size_t)NG * NNODE * 64 * 4);
  float* emb  = (float*)alloc((size_t)NG * BBATCH * DD * 4);
  float* pos  = (float*)alloc((size_t)BBATCH * 4);
  float* neg  = (float*)alloc((size_t)BBATCH * 4);
  int*   mode = (int*)alloc(256);

  const int* x0  = (const int*)d_in[9],  *x1 = (const int*)d_in[14], *x2 = (const int*)d_in[19];
  const int* ei0 = (const int*)d_in[10], *ei1 = (const int*)d_in[15], *ei2 = (const int*)d_in[20];
  const int* ea0 = (const int*)d_in[11], *ea1 = (const int*)d_in[16], *ea2 = (const int*)d_in[21];
  const int* y0  = (const int*)d_in[12], *y1 = (const int*)d_in[17], *y2 = (const int*)d_in[22];
  const int* s0  = (const int*)d_in[13], *s1 = (const int*)d_in[18], *s2 = (const int*)d_in[23];

  k_detect<<<1, 256, 0, stream>>>((const unsigned int*)ent, mode);
  k_pri<<<2, 256, 0, stream>>>(prior, mode, pris);
  k_rel<<<dim3(NRC, LLC, 2), DD, 0, stream>>>(rel, Wek, Wev, mode, relk, relv);
  hipMemsetAsync(deg, 0, (size_t)NG * NNODE * 4, stream);
  k_gather<<<dim3(NNODE * 64 / 256, NG), 256, 0, stream>>>(ent, x0, x1, x2, mode, h, hbf);
  k_bucket<<<dim3(EEDGE / 256, NG), 256, 0, stream>>>(ei0, ea0, ei1, ea1, ei2, ea2, deg, bucket);

  for (int l = 0; l < LLC; ++l) {
    k_gemm_qkv<<<dim3(NNODE / 64, 3, NG), 256, 0, stream>>>(hbf, Wq, Wk, Wv, mode, l, Qb, Kb, Vb);
    k_attn<<<dim3(NNODE / 4, NG), 256, 0, stream>>>(Qb, Kb, Vb, relk, relv, pris, deg, bucket, l, msgb);
    k_gemm_o<<<dim3(NNODE / 64, NG), 256, 0, stream>>>(msgb, Wo, mode, l, h, hbf);
  }
  k_extract<<<dim3(BBATCH, NG), DD, 0, stream>>>(h, y0, s0, y1, s1, y2, s2, emb);
  k_posneg<<<BBATCH, DD, 0, stream>>>(emb, emb + BBATCH * DD, emb + 2 * BBATCH * DD,
                                      rel, sample, mode, pos, neg);
  k_hinge<<<1, BBATCH, 0, stream>>>(pos, neg, mode, d_out);
}

// Round 6
// 530.256 us; speedup vs baseline: 1.9512x; 1.3981x over previous
//
#include <hip/hip_runtime.h>
#include <hip/hip_bf16.h>
#include <math.h>

#define NEC 200000
#define NRC 500
#define DD 128
#define LLC 2
#define NNODE 32768
#define EEDGE 262144
#define BBATCH 256
#define NG 3

typedef __attribute__((ext_vector_type(8))) short short8;
typedef __attribute__((ext_vector_type(4))) float floatx4;
typedef __attribute__((ext_vector_type(4))) unsigned short ushort4v;

__device__ __forceinline__ float bf2f(unsigned short u) {
  union { unsigned int i; float f; } c; c.i = ((unsigned int)u) << 16; return c.f;
}
__device__ __forceinline__ unsigned short f2bf(float f) {
  union { float f; unsigned int i; } c; c.f = f;
  unsigned int x = c.i;
  unsigned int r = x + 0x7fffu + ((x >> 16) & 1u);
  return (unsigned short)(r >> 16);
}
// bf16 pair unpack: low/high halves of a u32 as f32 (1 VALU op each)
__device__ __forceinline__ float bfu_lo(unsigned int u) {
  union { unsigned int i; float f; } c; c.i = u << 16; return c.f;
}
__device__ __forceinline__ float bfu_hi(unsigned int u) {
  union { unsigned int i; float f; } c; c.i = u & 0xffff0000u; return c.f;
}

// Detect input storage dtype (fp32 vs bf16); mode=1 -> fp32.
__global__ void k_detect(const unsigned int* ent_u32, int* mode) {
  int t = threadIdx.x;
  float best = 0.f;
  for (int i = 0; i < 16; ++i) {
    unsigned int w = ent_u32[t * 16 + i];
    float lo = fabsf(bf2f((unsigned short)(w & 0xffffu)));
    if (lo > best) best = lo;
  }
  for (int o = 32; o > 0; o >>= 1) {
    float n = __shfl_down(best, o);
    if (n > best) best = n;
  }
  __shared__ float wmax[4];
  if ((t & 63) == 0) wmax[t >> 6] = best;
  __syncthreads();
  if (t == 0) {
    float m = fmaxf(fmaxf(wmax[0], wmax[1]), fmaxf(wmax[2], wmax[3]));
    mode[0] = (m > 100.f) ? 1 : 0;
  }
}

__global__ void k_pri(const void* prior, const int* mode, float* pris) {
  int r = blockIdx.x * 256 + threadIdx.x;
  if (r >= NRC) return;
  float p = mode[0] ? ((const float*)prior)[r] : bf2f(((const unsigned short*)prior)[r]);
  pris[r] = p * 0.17677669529663687f; // 1/sqrt(32)
}

// Pre-transpose+convert Wq/Wk/Wv/Wo to bf16 once: WT[mat][l][d][c] = bf16(W[mat][l][c][d])
__global__ void k_wprep(const void* Wq, const void* Wk, const void* Wv, const void* Wo,
                        const int* mode, unsigned short* WT) {
  int mat = blockIdx.z, l = blockIdx.y;
  const void* W = mat == 0 ? Wq : (mat == 1 ? Wk : (mat == 2 ? Wv : Wo));
  bool fm = mode[0] != 0;
  int t = blockIdx.x * 256 + threadIdx.x; // 0..16383 = d*128+c
  int d = t >> 7, c = t & 127;
  size_t src = (size_t)l * DD * DD + (size_t)c * DD + d;
  float v = fm ? ((const float*)W)[src] : bf2f(((const unsigned short*)W)[src]);
  WT[(((size_t)mat * LLC + l) * DD + d) * DD + c] = f2bf(v);
}

// rel tables in bf16
__global__ void k_rel(const void* rel, const void* Wek, const void* Wev,
                      const int* mode, unsigned short* relk, unsigned short* relv) {
  int r = blockIdx.x, l = blockIdx.y, which = blockIdx.z;
  int d = threadIdx.x;
  bool fm = mode[0] != 0;
  size_t wofs = (size_t)l * DD * DD;
  const float* Wf = (const float*)(which ? Wev : Wek) + wofs;
  const unsigned short* Wb = (const unsigned short*)(which ? Wev : Wek) + wofs;
  __shared__ float re[DD];
  re[d] = fm ? ((const float*)rel)[r * DD + d] : bf2f(((const unsigned short*)rel)[r * DD + d]);
  __syncthreads();
  float acc = 0.f;
  if (fm) { for (int c = 0; c < DD; ++c) acc += re[c] * Wf[c * DD + d]; }
  else    { for (int c = 0; c < DD; ++c) acc += re[c] * bf2f(Wb[c * DD + d]); }
  unsigned short* out = which ? relv : relk;
  out[((size_t)l * NRC + r) * DD + d] = f2bf(acc);
}

// batched over graphs: blockIdx.y = graph
__global__ void k_gather(const void* ent, const int* x0, const int* x1, const int* x2,
                         const int* mode, float* h, unsigned short* hbf) {
  int g = blockIdx.y;
  const int* x = g == 0 ? x0 : (g == 1 ? x1 : x2);
  int t = blockIdx.x * 256 + threadIdx.x;
  int n = t >> 6, p = t & 63;
  int row = x[n];
  float2 f;
  if (mode[0]) {
    f = ((const float2*)((const float*)ent + (size_t)row * DD))[p];
  } else {
    unsigned int v = ((const unsigned int*)((const unsigned short*)ent + (size_t)row * DD))[p];
    f.x = bf2f((unsigned short)(v & 0xffffu));
    f.y = bf2f((unsigned short)(v >> 16));
  }
  size_t gi = (size_t)g * NNODE * 64 + t;
  ((unsigned int*)hbf)[gi] = ((unsigned int)f2bf(f.y) << 16) | (unsigned int)f2bf(f.x);
  ((float2*)h)[gi] = f;
}

// bucket entry packs src (15 bits) | rel (<<15); batched over graphs
__global__ void k_bucket(const int* ei0, const int* ea0, const int* ei1, const int* ea1,
                         const int* ei2, const int* ea2, int* deg, unsigned int* bucket) {
  int g = blockIdx.y;
  const int* ei = g == 0 ? ei0 : (g == 1 ? ei1 : ei2);
  const int* ea = g == 0 ? ea0 : (g == 1 ? ea1 : ea2);
  int e = blockIdx.x * 256 + threadIdx.x;
  if (e >= EEDGE) return;
  int dst = ei[EEDGE + e];
  int src = ei[e];
  int r = ea[e];
  int pos = atomicAdd(&deg[g * NNODE + dst], 1);
  if (pos < 64) bucket[((size_t)g * NNODE + dst) * 64 + pos] = (unsigned int)src | ((unsigned int)r << 15);
}

// stage pre-transposed bf16 W slice into LDS (pure vector copies)
__device__ __forceinline__ void stage_wt(const unsigned short* WT, int tid,
                                         unsigned short (*Wt)[136]) {
  #pragma unroll
  for (int pass = 0; pass < 8; ++pass) {
    int idx = pass * 256 + tid;
    int d = idx >> 4, c0 = (idx & 15) << 3;
    *reinterpret_cast<short8*>(&Wt[d][c0]) =
        *reinterpret_cast<const short8*>(WT + d * DD + c0);
  }
}

// Q/K/V GEMM batched: grid (512, 3=which, 3=graph)
__global__ __launch_bounds__(256) void k_gemm_qkv(const unsigned short* A,
    const unsigned short* WT, int layer, unsigned short* Qo, unsigned short* Ko,
    unsigned short* Vo) {
  __shared__ unsigned short Wt[DD][136];
  int mat = blockIdx.y;
  unsigned short* O = mat == 0 ? Qo : (mat == 1 ? Ko : Vo);
  int g = blockIdx.z;
  const unsigned short* Ag = A + (size_t)g * NNODE * DD;
  unsigned short* Og = O + (size_t)g * NNODE * DD;
  int tid = threadIdx.x;
  stage_wt(WT + ((size_t)mat * LLC + layer) * DD * DD, tid, Wt);
  __syncthreads();
  int w = tid >> 6, lane = tid & 63;
  int m = lane & 15, quad = lane >> 4;
  int row = blockIdx.x * 64 + w * 16 + m;
  floatx4 acc[8];
  #pragma unroll
  for (int t = 0; t < 8; ++t) acc[t] = (floatx4){0.f, 0.f, 0.f, 0.f};
  const unsigned short* arow = Ag + (size_t)row * DD;
  #pragma unroll
  for (int ks = 0; ks < 4; ++ks) {
    short8 a = *reinterpret_cast<const short8*>(arow + ks * 32 + quad * 8);
    #pragma unroll
    for (int t = 0; t < 8; ++t) {
      short8 b = *reinterpret_cast<const short8*>(&Wt[t * 16 + m][ks * 32 + quad * 8]);
      acc[t] = __builtin_amdgcn_mfma_f32_16x16x32_bf16(a, b, acc[t], 0, 0, 0);
    }
  }
  __syncthreads();
  unsigned short* ut = &Wt[0][0];
  #pragma unroll
  for (int t = 0; t < 8; ++t) {
    #pragma unroll
    for (int r = 0; r < 4; ++r) {
      ut[(w * 16 + quad * 4 + r) * 136 + t * 16 + m] = f2bf(acc[t][r]);
    }
  }
  __syncthreads();
  int rowbase = blockIdx.x * 64;
  #pragma unroll
  for (int k = 0; k < 4; ++k) {
    int flat = k * 256 + tid;
    int rw = flat >> 4, c8 = flat & 15;
    short8 v = *reinterpret_cast<const short8*>(ut + rw * 136 + c8 * 8);
    *reinterpret_cast<short8*>(Og + (size_t)(rowbase + rw) * DD + c8 * 8) = v;
  }
}

// h = gelu(h + msg @ Wo); batched: grid (512, 3=graph)
__global__ __launch_bounds__(256) void k_gemm_o(const unsigned short* A,
    const unsigned short* WT, int layer, float* h, unsigned short* hbf) {
  __shared__ unsigned short Wt[DD][136];
  int g = blockIdx.y;
  const unsigned short* Ag = A + (size_t)g * NNODE * DD;
  float* hg = h + (size_t)g * NNODE * DD;
  unsigned short* hbg = hbf + (size_t)g * NNODE * DD;
  int tid = threadIdx.x;
  stage_wt(WT + ((size_t)3 * LLC + layer) * DD * DD, tid, Wt);
  __syncthreads();
  int w = tid >> 6, lane = tid & 63;
  int m = lane & 15, quad = lane >> 4;
  int row = blockIdx.x * 64 + w * 16 + m;
  floatx4 acc[8];
  #pragma unroll
  for (int t = 0; t < 8; ++t) acc[t] = (floatx4){0.f, 0.f, 0.f, 0.f};
  const unsigned short* arow = Ag + (size_t)row * DD;
  #pragma unroll
  for (int ks = 0; ks < 4; ++ks) {
    short8 a = *reinterpret_cast<const short8*>(arow + ks * 32 + quad * 8);
    #pragma unroll
    for (int t = 0; t < 8; ++t) {
      short8 b = *reinterpret_cast<const short8*>(&Wt[t * 16 + m][ks * 32 + quad * 8]);
      acc[t] = __builtin_amdgcn_mfma_f32_16x16x32_bf16(a, b, acc[t], 0, 0, 0);
    }
  }
  __syncthreads();
  float* ft = (float*)&Wt[0][0];
  #pragma unroll
  for (int t = 0; t < 8; ++t) {
    #pragma unroll
    for (int r = 0; r < 4; ++r) {
      ft[(w * 16 + quad * 4 + r) * 136 + t * 16 + m] = acc[t][r];
    }
  }
  __syncthreads();
  int rowbase = blockIdx.x * 64;
  #pragma unroll
  for (int k = 0; k < 8; ++k) {
    int flat = k * 256 + tid;
    int rw = flat >> 5, c4 = flat & 31;
    float4 v = *reinterpret_cast<const float4*>(ft + rw * 136 + c4 * 4);
    size_t gi = (size_t)(rowbase + rw) * DD + c4 * 4;
    float4 hv = *reinterpret_cast<const float4*>(hg + gi);
    float4 res;
    {
      float xv = v.x + hv.x;
      res.x = 0.5f * xv * (1.f + tanhf(0.7978845608028654f * (xv + 0.044715f * xv * xv * xv)));
      xv = v.y + hv.y;
      res.y = 0.5f * xv * (1.f + tanhf(0.7978845608028654f * (xv + 0.044715f * xv * xv * xv)));
      xv = v.z + hv.z;
      res.z = 0.5f * xv * (1.f + tanhf(0.7978845608028654f * (xv + 0.044715f * xv * xv * xv)));
      xv = v.w + hv.w;
      res.w = 0.5f * xv * (1.f + tanhf(0.7978845608028654f * (xv + 0.044715f * xv * xv * xv)));
    }
    *reinterpret_cast<float4*>(hg + gi) = res;
    ushort4v b4 = { f2bf(res.x), f2bf(res.y), f2bf(res.z), f2bf(res.w) };
    *reinterpret_cast<ushort4v*>(hbg + gi) = b4;
  }
}

// one wave per dst node, 4 edges in flight: quarter = lane>>4 owns edge 4i+quarter,
// sl = lane&15 owns dims sl*8..sl*8+7 (uint4 = 8 bf16 per load). Head = sl>>2.
__global__ __launch_bounds__(256) void k_attn(const unsigned short* Q, const unsigned short* K,
    const unsigned short* V, const unsigned short* relk, const unsigned short* relv,
    const float* pris, const int* deg, const unsigned int* bucket, int layer,
    unsigned short* msgb) {
  int w = threadIdx.x >> 6, lane = threadIdx.x & 63;
  int quarter = lane >> 4, sl = lane & 15;
  int g = blockIdx.y;
  int dst = blockIdx.x * 4 + w;
  const unsigned short* rk = relk + (size_t)layer * NRC * DD;
  const unsigned short* rv = relv + (size_t)layer * NRC * DD;
  const unsigned short* Kg = K + (size_t)g * NNODE * DD;
  const unsigned short* Vg = V + (size_t)g * NNODE * DD;
  const unsigned short* Qg = Q + (size_t)g * NNODE * DD;

  uint4 qu = *reinterpret_cast<const uint4*>(Qg + (size_t)dst * DD + sl * 8);
  float q0 = bfu_lo(qu.x), q1 = bfu_hi(qu.x), q2 = bfu_lo(qu.y), q3 = bfu_hi(qu.y);
  float q4 = bfu_lo(qu.z), q5 = bfu_hi(qu.z), q6 = bfu_lo(qu.w), q7 = bfu_hi(qu.w);

  float den = 0.f;
  float m0 = 0.f, m1 = 0.f, m2 = 0.f, m3 = 0.f, m4 = 0.f, m5 = 0.f, m6 = 0.f, m7 = 0.f;
  int dg = deg[g * NNODE + dst]; if (dg > 64) dg = 64;
  size_t base = ((size_t)g * NNODE + dst) * 64;
  if (dg > 0) {
    int niter = (dg + 3) >> 2;
    int i0 = quarter < dg ? quarter : dg - 1;
    unsigned int pe = bucket[base + i0];
    for (int i = 0; i < niter; ++i) {
      unsigned int cur = pe;
      int nx = 4 * (i + 1) + quarter; if (nx >= dg) nx = dg - 1;
      pe = bucket[base + nx];
      int src = (int)(cur & 32767u);
      int r = (int)(cur >> 15);
      uint4 ku = *reinterpret_cast<const uint4*>(Kg + (size_t)src * DD + sl * 8);
      uint4 rku = *reinterpret_cast<const uint4*>(rk + (size_t)r * DD + sl * 8);
      uint4 vu = *reinterpret_cast<const uint4*>(Vg + (size_t)src * DD + sl * 8);
      uint4 rvu = *reinterpret_cast<const uint4*>(rv + (size_t)r * DD + sl * 8);
      float p = pris[r];
      float s = q0 * (bfu_lo(ku.x) + bfu_lo(rku.x))
              + q1 * (bfu_hi(ku.x) + bfu_hi(rku.x))
              + q2 * (bfu_lo(ku.y) + bfu_lo(rku.y))
              + q3 * (bfu_hi(ku.y) + bfu_hi(rku.y))
              + q4 * (bfu_lo(ku.z) + bfu_lo(rku.z))
              + q5 * (bfu_hi(ku.z) + bfu_hi(rku.z))
              + q6 * (bfu_lo(ku.w) + bfu_lo(rku.w))
              + q7 * (bfu_hi(ku.w) + bfu_hi(rku.w));
      s += __shfl_xor(s, 1); s += __shfl_xor(s, 2);   // reduce over 4-lane head group
      bool valid = (4 * i + quarter) < dg;
      float ex = valid ? __expf(s * p) : 0.f;
      den += ex;
      m0 += ex * (bfu_lo(vu.x) + bfu_lo(rvu.x));
      m1 += ex * (bfu_hi(vu.x) + bfu_hi(rvu.x));
      m2 += ex * (bfu_lo(vu.y) + bfu_lo(rvu.y));
      m3 += ex * (bfu_hi(vu.y) + bfu_hi(rvu.y));
      m4 += ex * (bfu_lo(vu.z) + bfu_lo(rvu.z));
      m5 += ex * (bfu_hi(vu.z) + bfu_hi(rvu.z));
      m6 += ex * (bfu_lo(vu.w) + bfu_lo(rvu.w));
      m7 += ex * (bfu_hi(vu.w) + bfu_hi(rvu.w));
    }
  }
  // combine the 4 edge-slots (lanes sl, sl+16, sl+32, sl+48 hold same dims)
  den += __shfl_xor(den, 16); den += __shfl_xor(den, 32);
  m0 += __shfl_xor(m0, 16); m0 += __shfl_xor(m0, 32);
  m1 += __shfl_xor(m1, 16); m1 += __shfl_xor(m1, 32);
  m2 += __shfl_xor(m2, 16); m2 += __shfl_xor(m2, 32);
  m3 += __shfl_xor(m3, 16); m3 += __shfl_xor(m3, 32);
  m4 += __shfl_xor(m4, 16); m4 += __shfl_xor(m4, 32);
  m5 += __shfl_xor(m5, 16); m5 += __shfl_xor(m5, 32);
  m6 += __shfl_xor(m6, 16); m6 += __shfl_xor(m6, 32);
  m7 += __shfl_xor(m7, 16); m7 += __shfl_xor(m7, 32);
  float inv = 1.f / (den + 1e-16f);
  if (quarter == 0) {
    uint4 o;
    o.x = ((unsigned int)f2bf(m1 * inv) << 16) | (unsigned int)f2bf(m0 * inv);
    o.y = ((unsigned int)f2bf(m3 * inv) << 16) | (unsigned int)f2bf(m2 * inv);
    o.z = ((unsigned int)f2bf(m5 * inv) << 16) | (unsigned int)f2bf(m4 * inv);
    o.w = ((unsigned int)f2bf(m7 * inv) << 16) | (unsigned int)f2bf(m6 * inv);
    *reinterpret_cast<uint4*>(msgb + (size_t)g * NNODE * DD + (size_t)dst * DD + sl * 8) = o;
  }
}

// batched extract: grid (256, 3)
__global__ void k_extract(const float* h, const int* y0, const int* s0,
                          const int* y1, const int* s1, const int* y2, const int* s2,
                          float* emb) {
  int g = blockIdx.y;
  const int* y = g == 0 ? y0 : (g == 1 ? y1 : y2);
  const int* s = g == 0 ? s0 : (g == 1 ? s1 : s2);
  int b = blockIdx.x, d = threadIdx.x;
  int offn = 0;
  for (int j = 0; j < b; ++j) offn += s[j];
  int idx = offn + y[b];
  emb[((size_t)g * BBATCH + b) * DD + d] = h[((size_t)g * NNODE + idx) * DD + d];
}

__global__ void k_posneg(const float* eh, const float* et, const float* en,
    const void* rel, const int* sample, const int* mode, float* pos, float* neg) {
  int b = blockIdx.x, d = threadIdx.x;
  bool fm = mode[0] != 0;
  int r = sample[b * 3 + 1];
  float tt = et[b * DD + d];
  float rr = fm ? ((const float*)rel)[r * DD + d] : bf2f(((const unsigned short*)rel)[r * DD + d]);
  float dp = tt - (eh[b * DD + d] + rr) + 1e-8f;
  float dn = tt - en[b * DD + d] + 1e-8f;
  float ap = dp * dp, an = dn * dn;
  for (int o = 32; o > 0; o >>= 1) { ap += __shfl_down(ap, o); an += __shfl_down(an, o); }
  __shared__ float sa[2], sb[2];
  if ((d & 63) == 0) { sa[d >> 6] = ap; sb[d >> 6] = an; }
  __syncthreads();
  if (d == 0) { pos[b] = sqrtf(sa[0] + sa[1]); neg[b] = sqrtf(sb[0] + sb[1]); }
}

__global__ __launch_bounds__(256) void k_hinge(const float* pos, const float* neg,
    const int* mode, void* out) {
  __shared__ float ns[BBATCH];
  __shared__ float wsum[4];
  int t = threadIdx.x;
  ns[t] = neg[t];
  float pb = pos[t];
  __syncthreads();
  float local = 0.f;
  for (int j = 0; j < BBATCH; ++j) {
    float v = pb - ns[j] + 1.0f;
    local += v > 0.f ? v : 0.f;
  }
  for (int o = 32; o > 0; o >>= 1) local += __shfl_down(local, o);
  if ((t & 63) == 0) wsum[t >> 6] = local;
  __syncthreads();
  if (t == 0) {
    float loss = (wsum[0] + wsum[1] + wsum[2] + wsum[3]) * (1.f / (256.f * 256.f));
    if (mode[0]) ((float*)out)[0] = loss;
    else         ((unsigned short*)out)[0] = f2bf(loss);
  }
}

extern "C" void kernel_launch(void* const* d_in, const int* in_sizes, int n_in,
                              void* d_out, int out_size, void* d_ws, size_t ws_size,
                              hipStream_t stream) {
  const void* ent   = d_in[0];
  const void* rel   = d_in[1];
  const void* prior = d_in[2];
  const void* Wq  = d_in[3];
  const void* Wk  = d_in[4];
  const void* Wv  = d_in[5];
  const void* Wo  = d_in[6];
  const void* Wek = d_in[7];
  const void* Wev = d_in[8];
  const int* sample = (const int*)d_in[24];

  size_t off = 0;
  char* basep = (char*)d_ws;
  auto alloc = [&](size_t bytes) -> void* {
    void* r = basep + off;
    off = (off + bytes + 255) & ~(size_t)255;
    return r;
  };
  float*          h    = (float*)alloc((size_t)NG * NNODE * DD * 4);
  unsigned short* hbf  = (unsigned short*)alloc((size_t)NG * NNODE * DD * 2);
  unsigned short* Qb   = (unsigned short*)alloc((size_t)NG * NNODE * DD * 2);
  unsigned short* Kb   = (unsigned short*)alloc((size_t)NG * NNODE * DD * 2);
  unsigned short* Vb   = (unsigned short*)alloc((size_t)NG * NNODE * DD * 2);
  unsigned short* msgb = (unsigned short*)alloc((size_t)NG * NNODE * DD * 2);
  unsigned short* relk = (unsigned short*)alloc((size_t)LLC * NRC * DD * 2);
  unsigned short* relv = (unsigned short*)alloc((size_t)LLC * NRC * DD * 2);
  unsigned short* WT   = (unsigned short*)alloc((size_t)4 * LLC * DD * DD * 2);
  float* pris = (float*)alloc((size_t)NRC * 4);
  int*   deg  = (int*)alloc((size_t)NG * NNODE * 4);
  unsigned int* bucket = (unsigned int*)alloc((size_t)NG * NNODE * 64 * 4);
  float* emb  = (float*)alloc((size_t)NG * BBATCH * DD * 4);
  float* pos  = (float*)alloc((size_t)BBATCH * 4);
  float* neg  = (float*)alloc((size_t)BBATCH * 4);
  int*   mode = (int*)alloc(256);

  const int* x0  = (const int*)d_in[9],  *x1 = (const int*)d_in[14], *x2 = (const int*)d_in[19];
  const int* ei0 = (const int*)d_in[10], *ei1 = (const int*)d_in[15], *ei2 = (const int*)d_in[20];
  const int* ea0 = (const int*)d_in[11], *ea1 = (const int*)d_in[16], *ea2 = (const int*)d_in[21];
  const int* y0  = (const int*)d_in[12], *y1 = (const int*)d_in[17], *y2 = (const int*)d_in[22];
  const int* s0  = (const int*)d_in[13], *s1 = (const int*)d_in[18], *s2 = (const int*)d_in[23];

  k_detect<<<1, 256, 0, stream>>>((const unsigned int*)ent, mode);
  k_pri<<<2, 256, 0, stream>>>(prior, mode, pris);
  k_wprep<<<dim3(64, LLC, 4), 256, 0, stream>>>(Wq, Wk, Wv, Wo, mode, WT);
  k_rel<<<dim3(NRC, LLC, 2), DD, 0, stream>>>(rel, Wek, Wev, mode, relk, relv);
  hipMemsetAsync(deg, 0, (size_t)NG * NNODE * 4, stream);
  k_gather<<<dim3(NNODE * 64 / 256, NG), 256, 0, stream>>>(ent, x0, x1, x2, mode, h, hbf);
  k_bucket<<<dim3(EEDGE / 256, NG), 256, 0, stream>>>(ei0, ea0, ei1, ea1, ei2, ea2, deg, bucket);

  for (int l = 0; l < LLC; ++l) {
    k_gemm_qkv<<<dim3(NNODE / 64, 3, NG), 256, 0, stream>>>(hbf, WT, l, Qb, Kb, Vb);
    k_attn<<<dim3(NNODE / 4, NG), 256, 0, stream>>>(Qb, Kb, Vb, relk, relv, pris, deg, bucket, l, msgb);
    k_gemm_o<<<dim3(NNODE / 64, NG), 256, 0, stream>>>(msgb, WT, l, h, hbf);
  }
  k_extract<<<dim3(BBATCH, NG), DD, 0, stream>>>(h, y0, s0, y1, s1, y2, s2, emb);
  k_posneg<<<BBATCH, DD, 0, stream>>>(emb, emb + BBATCH * DD, emb + 2 * BBATCH * DD,
                                      rel, sample, mode, pos, neg);
  k_hinge<<<1, BBATCH, 0, stream>>>(pos, neg, mode, d_out);
}